// Round 6
// baseline (287.828 us; speedup 1.0000x reference)
//
#include <hip/hip_runtime.h>

// Problem constants (from reference): B=16, T=512, D=8576.
#define N_ROWS 8192            // B*T
#define D_CH   8576
#define DV     (D_CH / 4)      // 2144 float4 columns
#define STATS_ROWS_PER_BLOCK 16
#define STATS_ROW_CHUNKS (N_ROWS / STATS_ROWS_PER_BLOCK)   // 512
#define APPLY_ROWS_PER_BLOCK 16
#define APPLY_ROW_CHUNKS (N_ROWS / APPLY_ROWS_PER_BLOCK)   // 512
#define EPSV 1e-5f
#define NOISE_STD 0.05f

typedef float f32x4 __attribute__((ext_vector_type(4)));

// ws layout (floats): [0,D) sum | [D,2D) sumsq   (scale/shift now fused into apply)

__global__ __launch_bounds__(256) void bn_partial_stats(
    const f32x4* __restrict__ x, float* __restrict__ ws_sum, float* __restrict__ ws_sq)
{
    int vc = blockIdx.x * blockDim.x + threadIdx.x;   // vec-channel
    if (vc >= DV) return;
    size_t base = (size_t)blockIdx.y * STATS_ROWS_PER_BLOCK * DV + vc;
    f32x4 s0 = (f32x4)0.f, s1 = (f32x4)0.f, s2 = (f32x4)0.f, s3 = (f32x4)0.f;
    f32x4 q0 = (f32x4)0.f, q1 = (f32x4)0.f, q2 = (f32x4)0.f, q3 = (f32x4)0.f;
    // 2 iterations; each batch-issues 8 independent loads before consuming.
#pragma unroll
    for (int r = 0; r < STATS_ROWS_PER_BLOCK; r += 8) {
        f32x4 v0 = x[base + (size_t)(r + 0) * DV];
        f32x4 v1 = x[base + (size_t)(r + 1) * DV];
        f32x4 v2 = x[base + (size_t)(r + 2) * DV];
        f32x4 v3 = x[base + (size_t)(r + 3) * DV];
        f32x4 v4 = x[base + (size_t)(r + 4) * DV];
        f32x4 v5 = x[base + (size_t)(r + 5) * DV];
        f32x4 v6 = x[base + (size_t)(r + 6) * DV];
        f32x4 v7 = x[base + (size_t)(r + 7) * DV];
        s0 += v0; q0 += v0 * v0;
        s1 += v1; q1 += v1 * v1;
        s2 += v2; q2 += v2 * v2;
        s3 += v3; q3 += v3 * v3;
        s0 += v4; q0 += v4 * v4;
        s1 += v5; q1 += v5 * v5;
        s2 += v6; q2 += v6 * v6;
        s3 += v7; q3 += v7 * v7;
    }
    f32x4 s = (s0 + s1) + (s2 + s3);
    f32x4 q = (q0 + q1) + (q2 + q3);
    int d0 = vc * 4;
    atomicAdd(&ws_sum[d0 + 0], s.x);
    atomicAdd(&ws_sum[d0 + 1], s.y);
    atomicAdd(&ws_sum[d0 + 2], s.z);
    atomicAdd(&ws_sum[d0 + 3], s.w);
    atomicAdd(&ws_sq[d0 + 0], q.x);
    atomicAdd(&ws_sq[d0 + 1], q.y);
    atomicAdd(&ws_sq[d0 + 2], q.z);
    atomicAdd(&ws_sq[d0 + 3], q.w);
}

// finalize fused: each thread derives scale/shift for its 4 channels from raw sums.
__global__ __launch_bounds__(256) void bn_apply(
    const f32x4* __restrict__ x, const f32x4* __restrict__ noise,
    const f32x4* __restrict__ ws_sum4, const f32x4* __restrict__ ws_sq4,
    const f32x4* __restrict__ gamma4, const f32x4* __restrict__ beta4,
    f32x4* __restrict__ out)
{
    int vc = blockIdx.x * blockDim.x + threadIdx.x;
    if (vc >= DV) return;

    const float invN = 1.0f / (float)N_ROWS;
    f32x4 sm = ws_sum4[vc];          // L2/L3-resident, 34 KB
    f32x4 sq = ws_sq4[vc];
    f32x4 gm = gamma4[vc];
    f32x4 bt = beta4[vc];
    f32x4 mu = sm * invN;
    f32x4 var = sq * invN - mu * mu;
    f32x4 sc, sh;
    sc.x = gm.x * rsqrtf(var.x + EPSV);
    sc.y = gm.y * rsqrtf(var.y + EPSV);
    sc.z = gm.z * rsqrtf(var.z + EPSV);
    sc.w = gm.w * rsqrtf(var.w + EPSV);
    sh = bt - mu * sc;

    size_t base = (size_t)blockIdx.y * APPLY_ROWS_PER_BLOCK * DV + vc;
    // Two half-batches of 8 rows: 16 loads in flight, then 8 computes+stores.
#pragma unroll
    for (int h = 0; h < 2; ++h) {
        size_t b = base + (size_t)(h * 8) * DV;
        f32x4 xv[8], nv[8];
#pragma unroll
        for (int r = 0; r < 8; ++r) {
            xv[r] = x[b + (size_t)r * DV];                                   // cached: L3-resident
            nv[r] = __builtin_nontemporal_load(&noise[b + (size_t)r * DV]);  // stream once
        }
#pragma unroll
        for (int r = 0; r < 8; ++r) {
            f32x4 o = xv[r] * sc + sh + nv[r] * NOISE_STD;
            __builtin_nontemporal_store(o, &out[b + (size_t)r * DV]);        // never re-read
        }
    }
}

extern "C" void kernel_launch(void* const* d_in, const int* in_sizes, int n_in,
                              void* d_out, int out_size, void* d_ws, size_t ws_size,
                              hipStream_t stream) {
    const float* x     = (const float*)d_in[0];
    const float* noise = (const float*)d_in[1];
    const float* gamma = (const float*)d_in[2];
    const float* beta  = (const float*)d_in[3];
    float* out = (float*)d_out;

    float* ws       = (float*)d_ws;
    float* ws_sum   = ws;
    float* ws_sq    = ws + D_CH;

    // Zero the accumulators (stream-ordered, capture-safe).
    (void)hipMemsetAsync(d_ws, 0, 2 * D_CH * sizeof(float), stream);

    dim3 blk(256, 1, 1);
    dim3 grd_stats((DV + 255) / 256, STATS_ROW_CHUNKS, 1);   // 9 x 512
    bn_partial_stats<<<grd_stats, blk, 0, stream>>>((const f32x4*)x, ws_sum, ws_sq);

    dim3 grd_apply((DV + 255) / 256, APPLY_ROW_CHUNKS, 1);   // 9 x 512
    bn_apply<<<grd_apply, blk, 0, stream>>>((const f32x4*)x, (const f32x4*)noise,
                                            (const f32x4*)ws_sum, (const f32x4*)ws_sq,
                                            (const f32x4*)gamma, (const f32x4*)beta,
                                            (f32x4*)out);
}

// Round 7
// 264.323 us; speedup vs baseline: 1.0889x; 1.0889x over previous
//
#include <hip/hip_runtime.h>

// Problem constants (from reference): B=16, T=512, D=8576.
#define N_ROWS 8192            // B*T
#define D_CH   8576
#define DV     (D_CH / 4)      // 2144 float4 columns
#define STATS_ROWS_PER_BLOCK 16
#define STATS_ROW_CHUNKS (N_ROWS / STATS_ROWS_PER_BLOCK)   // 512
#define APPLY_ROWS_PER_BLOCK 16
#define APPLY_ROW_CHUNKS (N_ROWS / APPLY_ROWS_PER_BLOCK)   // 512
#define EPSV 1e-5f
#define NOISE_STD 0.05f
#define MAX_SPREAD 32

typedef float f32x4 __attribute__((ext_vector_type(4)));

// ws layout (floats):
//   [0, nspread*2*D)                      : partial accumulators, copy c at c*2*D (sum then sumsq)
//   [nspread*2*D, nspread*2*D + D)        : scale
//   [nspread*2*D + D, nspread*2*D + 2*D)  : shift

__global__ __launch_bounds__(256) void bn_partial_stats(
    const f32x4* __restrict__ x, float* __restrict__ part, int spread_mask)
{
    int vc = blockIdx.x * blockDim.x + threadIdx.x;   // vec-channel
    if (vc >= DV) return;
    size_t base = (size_t)blockIdx.y * STATS_ROWS_PER_BLOCK * DV + vc;
    f32x4 s0 = (f32x4)0.f, s1 = (f32x4)0.f, s2 = (f32x4)0.f, s3 = (f32x4)0.f;
    f32x4 q0 = (f32x4)0.f, q1 = (f32x4)0.f, q2 = (f32x4)0.f, q3 = (f32x4)0.f;
#pragma unroll
    for (int r = 0; r < STATS_ROWS_PER_BLOCK; r += 8) {
        f32x4 v0 = x[base + (size_t)(r + 0) * DV];
        f32x4 v1 = x[base + (size_t)(r + 1) * DV];
        f32x4 v2 = x[base + (size_t)(r + 2) * DV];
        f32x4 v3 = x[base + (size_t)(r + 3) * DV];
        f32x4 v4 = x[base + (size_t)(r + 4) * DV];
        f32x4 v5 = x[base + (size_t)(r + 5) * DV];
        f32x4 v6 = x[base + (size_t)(r + 6) * DV];
        f32x4 v7 = x[base + (size_t)(r + 7) * DV];
        s0 += v0; q0 += v0 * v0;
        s1 += v1; q1 += v1 * v1;
        s2 += v2; q2 += v2 * v2;
        s3 += v3; q3 += v3 * v3;
        s0 += v4; q0 += v4 * v4;
        s1 += v5; q1 += v5 * v5;
        s2 += v6; q2 += v6 * v6;
        s3 += v7; q3 += v7 * v7;
    }
    f32x4 s = (s0 + s1) + (s2 + s3);
    f32x4 q = (q0 + q1) + (q2 + q3);
    // spread atomics over copies: contention depth = ROW_CHUNKS / nspread (= 16 at spread 32)
    float* cp = part + (size_t)(blockIdx.y & spread_mask) * (2 * D_CH);
    int d0 = vc * 4;
    atomicAdd(&cp[d0 + 0], s.x);
    atomicAdd(&cp[d0 + 1], s.y);
    atomicAdd(&cp[d0 + 2], s.z);
    atomicAdd(&cp[d0 + 3], s.w);
    atomicAdd(&cp[D_CH + d0 + 0], q.x);
    atomicAdd(&cp[D_CH + d0 + 1], q.y);
    atomicAdd(&cp[D_CH + d0 + 2], q.z);
    atomicAdd(&cp[D_CH + d0 + 3], q.w);
}

__global__ __launch_bounds__(256) void bn_finalize(
    const float* __restrict__ part,
    const float* __restrict__ gamma, const float* __restrict__ beta,
    float* __restrict__ ws_scale, float* __restrict__ ws_shift, int nspread)
{
    int d = blockIdx.x * blockDim.x + threadIdx.x;
    if (d >= D_CH) return;
    float s = 0.f, q = 0.f;
    for (int c = 0; c < nspread; ++c) {
        s += part[(size_t)c * (2 * D_CH) + d];
        q += part[(size_t)c * (2 * D_CH) + D_CH + d];
    }
    const float invN = 1.0f / (float)N_ROWS;
    float mu  = s * invN;
    float var = q * invN - mu * mu;
    float sc  = gamma[d] * rsqrtf(var + EPSV);
    ws_scale[d] = sc;
    ws_shift[d] = beta[d] - mu * sc;
}

__global__ __launch_bounds__(256) void bn_apply(
    const f32x4* __restrict__ x, const f32x4* __restrict__ noise,
    const f32x4* __restrict__ ws_scale4, const f32x4* __restrict__ ws_shift4,
    f32x4* __restrict__ out)
{
    int vc = blockIdx.x * blockDim.x + threadIdx.x;
    if (vc >= DV) return;
    f32x4 sc = ws_scale4[vc];
    f32x4 sh = ws_shift4[vc];
    size_t base = (size_t)blockIdx.y * APPLY_ROWS_PER_BLOCK * DV + vc;
    // Two half-batches of 8 rows: 16 loads in flight, then 8 computes+stores.
#pragma unroll
    for (int h = 0; h < 2; ++h) {
        size_t b = base + (size_t)(h * 8) * DV;
        f32x4 xv[8], nv[8];
#pragma unroll
        for (int r = 0; r < 8; ++r) {
            xv[r] = x[b + (size_t)r * DV];                                   // cached: L3-resident
            nv[r] = __builtin_nontemporal_load(&noise[b + (size_t)r * DV]);  // stream once
        }
#pragma unroll
        for (int r = 0; r < 8; ++r) {
            f32x4 o = xv[r] * sc + sh + nv[r] * NOISE_STD;
            __builtin_nontemporal_store(o, &out[b + (size_t)r * DV]);        // never re-read
        }
    }
}

extern "C" void kernel_launch(void* const* d_in, const int* in_sizes, int n_in,
                              void* d_out, int out_size, void* d_ws, size_t ws_size,
                              hipStream_t stream) {
    const float* x     = (const float*)d_in[0];
    const float* noise = (const float*)d_in[1];
    const float* gamma = (const float*)d_in[2];
    const float* beta  = (const float*)d_in[3];
    float* out = (float*)d_out;

    // pick largest power-of-2 spread whose ws footprint fits
    int nspread = MAX_SPREAD;
    while (nspread > 1 &&
           ((size_t)nspread * 2 * D_CH + 2 * D_CH) * sizeof(float) > ws_size)
        nspread >>= 1;

    float* ws       = (float*)d_ws;
    float* part     = ws;
    float* ws_scale = ws + (size_t)nspread * 2 * D_CH;
    float* ws_shift = ws_scale + D_CH;

    // Zero the partial accumulators (stream-ordered, capture-safe).
    (void)hipMemsetAsync(d_ws, 0, (size_t)nspread * 2 * D_CH * sizeof(float), stream);

    dim3 blk(256, 1, 1);
    dim3 grd_stats((DV + 255) / 256, STATS_ROW_CHUNKS, 1);   // 9 x 512
    bn_partial_stats<<<grd_stats, blk, 0, stream>>>((const f32x4*)x, part, nspread - 1);

    dim3 grd_fin((D_CH + 255) / 256, 1, 1);                  // 34
    bn_finalize<<<grd_fin, blk, 0, stream>>>(part, gamma, beta, ws_scale, ws_shift, nspread);

    dim3 grd_apply((DV + 255) / 256, APPLY_ROW_CHUNKS, 1);   // 9 x 512
    bn_apply<<<grd_apply, blk, 0, stream>>>((const f32x4*)x, (const f32x4*)noise,
                                            (const f32x4*)ws_scale, (const f32x4*)ws_shift,
                                            (f32x4*)out);
}

// Round 8
// 199.483 us; speedup vs baseline: 1.4429x; 1.3250x over previous
//
#include <hip/hip_runtime.h>

// Problem constants (from reference): B=16, T=512, D=8576.
#define N_ROWS 8192            // B*T
#define D_CH   8576
#define DV     (D_CH / 4)      // 2144 float4 columns
#define MAX_CHUNKS 128         // stats row-chunks (64 rows each); halved if ws too small
#define APPLY_ROWS_PER_BLOCK 16
#define APPLY_ROW_CHUNKS (N_ROWS / APPLY_ROWS_PER_BLOCK)   // 512
#define EPSV 1e-5f
#define NOISE_STD 0.05f

typedef float f32x4 __attribute__((ext_vector_type(4)));

// ws layout (f32x4 units):
//   [0, nchunks*2*DV)      : per-chunk partials; chunk c: sums at c*2*DV, sumsq at c*2*DV+DV
//   then scale4 [DV], shift4 [DV]
// NO atomics anywhere; no ws zeroing required (every slot written unconditionally).

__global__ __launch_bounds__(256) void bn_partial_stats(
    const f32x4* __restrict__ x, f32x4* __restrict__ part, int rows_per_block)
{
    int vc = blockIdx.x * blockDim.x + threadIdx.x;   // vec-channel
    if (vc >= DV) return;
    size_t base = (size_t)blockIdx.y * rows_per_block * DV + vc;
    f32x4 s0 = (f32x4)0.f, s1 = (f32x4)0.f, s2 = (f32x4)0.f, s3 = (f32x4)0.f;
    f32x4 q0 = (f32x4)0.f, q1 = (f32x4)0.f, q2 = (f32x4)0.f, q3 = (f32x4)0.f;
    for (int r = 0; r < rows_per_block; r += 8) {
        size_t b = base + (size_t)r * DV;
        f32x4 v0 = x[b + 0 * (size_t)DV];
        f32x4 v1 = x[b + 1 * (size_t)DV];
        f32x4 v2 = x[b + 2 * (size_t)DV];
        f32x4 v3 = x[b + 3 * (size_t)DV];
        f32x4 v4 = x[b + 4 * (size_t)DV];
        f32x4 v5 = x[b + 5 * (size_t)DV];
        f32x4 v6 = x[b + 6 * (size_t)DV];
        f32x4 v7 = x[b + 7 * (size_t)DV];
        s0 += v0; q0 += v0 * v0;
        s1 += v1; q1 += v1 * v1;
        s2 += v2; q2 += v2 * v2;
        s3 += v3; q3 += v3 * v3;
        s0 += v4; q0 += v4 * v4;
        s1 += v5; q1 += v5 * v5;
        s2 += v6; q2 += v6 * v6;
        s3 += v7; q3 += v7 * v7;
    }
    f32x4 s = (s0 + s1) + (s2 + s3);
    f32x4 q = (q0 + q1) + (q2 + q3);
    // unique slot per chunk: plain coalesced stores, no atomics
    size_t slot = (size_t)blockIdx.y * (2 * DV) + vc;
    part[slot]      = s;
    part[slot + DV] = q;
}

__global__ __launch_bounds__(256) void bn_finalize(
    const f32x4* __restrict__ part,
    const f32x4* __restrict__ gamma4, const f32x4* __restrict__ beta4,
    f32x4* __restrict__ ws_scale, f32x4* __restrict__ ws_shift, int nchunks)
{
    int vc = blockIdx.x * blockDim.x + threadIdx.x;
    if (vc >= DV) return;
    f32x4 s = (f32x4)0.f, q = (f32x4)0.f;
    // independent strided loads; batch 4 chunks per iteration for MLP
    for (int c = 0; c < nchunks; c += 4) {
        size_t b0 = (size_t)(c + 0) * (2 * DV) + vc;
        size_t b1 = (size_t)(c + 1) * (2 * DV) + vc;
        size_t b2 = (size_t)(c + 2) * (2 * DV) + vc;
        size_t b3 = (size_t)(c + 3) * (2 * DV) + vc;
        f32x4 sa = part[b0], qa = part[b0 + DV];
        f32x4 sb = part[b1], qb = part[b1 + DV];
        f32x4 sc_ = part[b2], qc = part[b2 + DV];
        f32x4 sd = part[b3], qd = part[b3 + DV];
        s += (sa + sb) + (sc_ + sd);
        q += (qa + qb) + (qc + qd);
    }
    const float invN = 1.0f / (float)N_ROWS;
    f32x4 mu = s * invN;
    f32x4 var = q * invN - mu * mu;
    f32x4 gm = gamma4[vc];
    f32x4 bt = beta4[vc];
    f32x4 sc;
    sc.x = gm.x * rsqrtf(var.x + EPSV);
    sc.y = gm.y * rsqrtf(var.y + EPSV);
    sc.z = gm.z * rsqrtf(var.z + EPSV);
    sc.w = gm.w * rsqrtf(var.w + EPSV);
    ws_scale[vc] = sc;
    ws_shift[vc] = bt - mu * sc;
}

__global__ __launch_bounds__(256) void bn_apply(
    const f32x4* __restrict__ x, const f32x4* __restrict__ noise,
    const f32x4* __restrict__ ws_scale4, const f32x4* __restrict__ ws_shift4,
    f32x4* __restrict__ out)
{
    int vc = blockIdx.x * blockDim.x + threadIdx.x;
    if (vc >= DV) return;
    f32x4 sc = ws_scale4[vc];
    f32x4 sh = ws_shift4[vc];
    size_t base = (size_t)blockIdx.y * APPLY_ROWS_PER_BLOCK * DV + vc;
    // Two half-batches of 8 rows: 16 loads in flight, then 8 computes+stores.
#pragma unroll
    for (int h = 0; h < 2; ++h) {
        size_t b = base + (size_t)(h * 8) * DV;
        f32x4 xv[8], nv[8];
#pragma unroll
        for (int r = 0; r < 8; ++r) {
            xv[r] = x[b + (size_t)r * DV];                                   // cached: L3-resident
            nv[r] = __builtin_nontemporal_load(&noise[b + (size_t)r * DV]);  // stream once
        }
#pragma unroll
        for (int r = 0; r < 8; ++r) {
            f32x4 o = xv[r] * sc + sh + nv[r] * NOISE_STD;
            __builtin_nontemporal_store(o, &out[b + (size_t)r * DV]);        // never re-read
        }
    }
}

extern "C" void kernel_launch(void* const* d_in, const int* in_sizes, int n_in,
                              void* d_out, int out_size, void* d_ws, size_t ws_size,
                              hipStream_t stream) {
    const float* x     = (const float*)d_in[0];
    const float* noise = (const float*)d_in[1];
    const float* gamma = (const float*)d_in[2];
    const float* beta  = (const float*)d_in[3];
    float* out = (float*)d_out;

    // largest power-of-2 chunk count whose partials + scale/shift fit in ws
    int nchunks = MAX_CHUNKS;
    while (nchunks > 4 &&
           ((size_t)nchunks * 2 * DV + 2 * DV) * sizeof(f32x4) > ws_size)
        nchunks >>= 1;
    int rows_per_block = N_ROWS / nchunks;

    f32x4* part     = (f32x4*)d_ws;
    f32x4* ws_scale = part + (size_t)nchunks * 2 * DV;
    f32x4* ws_shift = ws_scale + DV;

    dim3 blk(256, 1, 1);
    dim3 grd_stats((DV + 255) / 256, nchunks, 1);            // 9 x 128
    bn_partial_stats<<<grd_stats, blk, 0, stream>>>((const f32x4*)x, part, rows_per_block);

    dim3 grd_fin((DV + 255) / 256, 1, 1);                    // 9
    bn_finalize<<<grd_fin, blk, 0, stream>>>(part, (const f32x4*)gamma, (const f32x4*)beta,
                                             ws_scale, ws_shift, nchunks);

    dim3 grd_apply((DV + 255) / 256, APPLY_ROW_CHUNKS, 1);   // 9 x 512
    bn_apply<<<grd_apply, blk, 0, stream>>>((const f32x4*)x, (const f32x4*)noise,
                                            (const f32x4*)ws_scale, (const f32x4*)ws_shift,
                                            (f32x4*)out);
}